// Round 7
// baseline (445.016 us; speedup 1.0000x reference)
//
#include <hip/hip_runtime.h>

#define HW_IMG (224*224)
#define SCALE 0.17677669529663687f   // 1/sqrt(32)

typedef short bf16x8 __attribute__((ext_vector_type(8)));
typedef float f32x4 __attribute__((ext_vector_type(4)));
union U4B8 { uint4 u; bf16x8 b; };

__device__ __forceinline__ unsigned bf16rn(float f) {
  unsigned u = __float_as_uint(f);
  return (u + 0x7fffu + ((u >> 16) & 1u)) >> 16;
}
__device__ __forceinline__ unsigned packbf(float a, float b) {
  return bf16rn(a) | (bf16rn(b) << 16);
}

// ---- prep1: qh[r] = in_b[r] + query.in_w[r,:]; cb[r] = out_b[r] + out_w[r,:].aob ----
__global__ void prep1_kernel(const float* __restrict__ query,
                             const float* __restrict__ in_w,
                             const float* __restrict__ in_b,
                             const float* __restrict__ out_w,
                             const float* __restrict__ aob,
                             const float* __restrict__ out_b,
                             float* __restrict__ qh,
                             float* __restrict__ cb) {
  const int r = blockIdx.x, tid = threadIdx.x;
  float p1 = query[tid] * in_w[r*256 + tid];
  float p2 = aob[tid]   * out_w[r*256 + tid];
  #pragma unroll
  for (int o = 32; o; o >>= 1) { p1 += __shfl_xor(p1, o); p2 += __shfl_xor(p2, o); }
  __shared__ float t1[4], t2[4];
  if ((tid & 63) == 0) { t1[tid>>6] = p1; t2[tid>>6] = p2; }
  __syncthreads();
  if (tid == 0) qh[r] = in_b[r] + t1[0]+t1[1]+t1[2]+t1[3];
  if (tid == 1) cb[r] = out_b[r] + t2[0]+t2[1]+t2[2]+t2[3];
}

// ---- prep2: qk2g bf16 [16][256], rows 8..15 zero; qk2g[h][c] = SCALE*qh_h . wk_h[:,c] ----
__global__ void prep2_kernel(const float* __restrict__ qh,
                             const float* __restrict__ in_w,
                             unsigned short* __restrict__ qk2g) {
  const int h = blockIdx.x;   // 0..15
  const int c = threadIdx.x;  // 0..255
  float s = 0.f;
  if (h < 8) {
    #pragma unroll
    for (int d = 0; d < 32; ++d)
      s += qh[h*32 + d] * in_w[(256 + h*32 + d)*256 + c];
    s *= SCALE;
  }
  qk2g[h*256 + c] = (unsigned short)bf16rn(s);
}

// ---- prep3: cwT[t][o] = (out_w @ attn_out_w)[o][t] ----
__global__ void prep3_kernel(const float* __restrict__ aw,
                             const float* __restrict__ out_w,
                             float* __restrict__ cwT) {
  const int o = blockIdx.x, t = threadIdx.x;
  float a = 0.f;
  #pragma unroll 4
  for (int k = 0; k < 256; ++k) a += out_w[o*256 + k] * aw[k*256 + t];
  cwT[t*256 + o] = a;
}

// ---- K1: block=(b,cg,pi). Streams X, emits Y' (c-major bf16, c-pair interleaved)
//      and all scores Sp (fp32) via MFMA. 8 col-tiles of 28 cols x 14 rows. ----
__global__ __launch_bounds__(256)
__attribute__((amdgpu_waves_per_eu(2, 8)))
void k1_repack_scores(const float* __restrict__ X,
                      const unsigned short* __restrict__ qk2g,
                      unsigned short* __restrict__ Yp,
                      float* __restrict__ Sp) {
  __shared__ unsigned Tt[400*36];     // [pos 392(+8)][c2 32(+4 pad)] bf16-pairs
  __shared__ float sps[8*404];        // [h][pos 400]
  __shared__ unsigned qk_l[16*36];    // [h16][c2 32(+4)] bf16-pairs

  const int tid = threadIdx.x;
  const int lane = tid & 63;
  const int wid = tid >> 6;
  const int bx = blockIdx.x;
  const int g = (bx & 7)*64 + (bx >> 3);   // XCD swizzle (512 = 8*64)
  const int cg = g & 3;
  const int rest = g >> 2;                 // 0..127
  const int pi = rest & 15, b = rest >> 4;

  // stage qk_l (bf16-pairs) from qk2g
  #pragma unroll
  for (int i = 0; i < 2; ++i) {
    const int u = tid + 256*i;             // < 512
    const int h = u >> 5, cl2 = u & 31;
    qk_l[h*36 + cl2] = *(const unsigned*)(qk2g + h*256 + cg*64 + 2*cl2);
  }
  __syncthreads();

  // hoisted qk A-fragments: lane(h=lane&15, kq=lane>>4), ksteps 0,1
  U4B8 a0, a1;
  a0.u = *(const uint4*)&qk_l[(lane & 15)*36 + (lane >> 4)*4];
  a1.u = *(const uint4*)&qk_l[(lane & 15)*36 + 16 + (lane >> 4)*4];

  const int c2 = tid & 31, q = tid >> 5;   // loader mapping
  const float* xc0 = X + (size_t)(b*256 + cg*64 + 2*c2)*HW_IMG + pi*14*224;
  const float* xc1 = xc0 + HW_IMG;

  #pragma unroll 1
  for (int ct = 0; ct < 8; ++ct) {
    // ---- P1: load 64ch x 14r x 28col fp32, pack bf16 pairs into Tt[pos][c2] ----
    #pragma unroll
    for (int r = 0; r < 14; ++r) {
      #pragma unroll
      for (int j = 0; j < 2; ++j) {
        const int f = q + 8*j;             // col-pair index
        if (f < 14) {
          const int off = r*224 + ct*28 + 2*f;
          const float2 v0 = *(const float2*)(xc0 + off);
          const float2 v1 = *(const float2*)(xc1 + off);
          const int pos = r*28 + 2*f;
          Tt[pos*36 + c2]     = packbf(v0.x, v1.x);
          Tt[(pos+1)*36 + c2] = packbf(v0.y, v1.y);
        }
      }
    }
    __syncthreads();   // barA: Tt ready

    // ---- P2a: MFMA scores D[h][pos] -> sps ----
    for (int ti = wid; ti < 25; ti += 4) {
      U4B8 b0, b1;
      const int prow = ti*16 + (lane & 15);
      b0.u = *(const uint4*)&Tt[prow*36 + (lane >> 4)*4];
      b1.u = *(const uint4*)&Tt[prow*36 + 16 + (lane >> 4)*4];
      f32x4 d = {0.f, 0.f, 0.f, 0.f};
      d = __builtin_amdgcn_mfma_f32_16x16x32_bf16(a0.b, b0.b, d, 0, 0, 0);
      d = __builtin_amdgcn_mfma_f32_16x16x32_bf16(a1.b, b1.b, d, 0, 0, 0);
      if ((lane >> 4) < 2) {
        const int h = (lane >> 4)*4;
        const int pp = ti*16 + (lane & 15);
        sps[(h+0)*404 + pp] = d[0];
        sps[(h+1)*404 + pp] = d[1];
        sps[(h+2)*404 + pp] = d[2];
        sps[(h+3)*404 + pp] = d[3];
      }
    }

    // ---- P2b: Y' write: runs of 16 bf16-pairs (64B) per (c2, pj, r) ----
    #pragma unroll
    for (int k = 0; k < 4; ++k) {
      const int id = tid + 256*k;
      if (id < 896) {
        const int c2l = id & 31, pj2 = (id >> 5) & 1, r = id >> 6;
        unsigned w[16];
        #pragma unroll
        for (int jj = 0; jj < 14; ++jj)
          w[jj] = Tt[(r*28 + pj2*14 + jj)*36 + c2l];
        w[14] = 0u; w[15] = 0u;
        const int n = (b*16 + pi)*16 + ct*2 + pj2;
        unsigned short* dst = Yp + (size_t)n*57344 + (cg*32 + c2l)*448 + 32*r;
        *(uint4*)(dst)      = make_uint4(w[0],  w[1],  w[2],  w[3]);
        *(uint4*)(dst + 8)  = make_uint4(w[4],  w[5],  w[6],  w[7]);
        *(uint4*)(dst + 16) = make_uint4(w[8],  w[9],  w[10], w[11]);
        *(uint4*)(dst + 24) = make_uint4(w[12], w[13], w[14], w[15]);
      }
    }
    __syncthreads();   // barB: sps ready, Tt consumed

    // ---- P3: Sp write-out, 64B runs with zeroed holes ----
    {
      const int h = tid & 7, r = (tid >> 3) & 15, pj2 = (tid >> 7) & 1;
      if (r < 14) {
        float s[16];
        #pragma unroll
        for (int jj = 0; jj < 14; ++jj)
          s[jj] = sps[h*404 + r*28 + pj2*14 + jj];
        s[14] = 0.f; s[15] = 0.f;
        const int n = (b*16 + pi)*16 + ct*2 + pj2;
        float* dst = Sp + ((size_t)(cg*2048 + n)*8 + h)*224 + 16*r;
        *(float4*)(dst)      = make_float4(s[0],  s[1],  s[2],  s[3]);
        *(float4*)(dst + 4)  = make_float4(s[4],  s[5],  s[6],  s[7]);
        *(float4*)(dst + 8)  = make_float4(s[8],  s[9],  s[10], s[11]);
        *(float4*)(dst + 12) = make_float4(s[12], s[13], s[14], s[15]);
      }
    }
    __syncthreads();   // barC: sps consumed
  }
}

// ---- K2: per-patch. Sp-reduce -> softmax -> normalized bf16 weights ->
//      pooling GEMM with A-frags direct from global Y'. pooled fp32 out. ----
__global__ __launch_bounds__(256)
__attribute__((amdgpu_waves_per_eu(2, 8)))
void k2_pool(const unsigned short* __restrict__ Yp,
             const float* __restrict__ Sp,
             float* __restrict__ pooled) {
  __shared__ float sm[1792];          // summed scores [h*224 + L]
  __shared__ unsigned aw[16*116];     // bf16-pair weights [h16][L-pair 112(+4)]
  __shared__ float pool_s[8*260];

  const int tid = threadIdx.x;
  const int lane = tid & 63, wid = tid >> 6;
  const int bid = blockIdx.x;
  const int n = (bid & 7)*256 + (bid >> 3);   // XCD swizzle

  // zero aw rows 8..15
  #pragma unroll
  for (int i = 0; i < 4; ++i) {
    const int u = tid + 256*i;
    if (u < 928) aw[928 + u] = 0u;
  }

  // phase 1: reduce Sp over cg
  const float* spn = Sp + (size_t)n*1792;
  #pragma unroll
  for (int j = 0; j < 7; ++j) {
    const int idx = tid + 256*j;
    sm[idx] = spn[idx] + spn[3670016 + idx] + spn[2*3670016 + idx] + spn[3*3670016 + idx];
  }
  __syncthreads();

  // phase 2: softmax per head (32 lanes per head), normalized bf16 weights
  {
    const int h = tid >> 5, l = tid & 31;
    float sv[7]; bool msk[7];
    float mx = -1e30f;
    #pragma unroll
    for (int j = 0; j < 7; ++j) {
      const int L = l + 32*j;
      sv[j] = sm[h*224 + L];
      msk[j] = (L & 15) < 14;
      if (msk[j]) mx = fmaxf(mx, sv[j]);
    }
    #pragma unroll
    for (int o = 16; o; o >>= 1) mx = fmaxf(mx, __shfl_xor(mx, o, 32));
    float d = 0.f;
    #pragma unroll
    for (int j = 0; j < 7; ++j) {
      sv[j] = msk[j] ? __expf(sv[j] - mx) : 0.f;
      d += sv[j];
    }
    #pragma unroll
    for (int o = 16; o; o >>= 1) d += __shfl_xor(d, o, 32);
    const float inv = 1.f / d;
    #pragma unroll
    for (int j = 0; j < 7; ++j) {
      const float w = sv[j] * inv;
      const float wn = __shfl_xor(w, 1, 32);
      if ((l & 1) == 0) aw[h*116 + ((l + 32*j) >> 1)] = packbf(w, wn);
    }
  }
  __syncthreads();

  // phase 3: pooling. D[c][h] = sum_L Y'[c][L] * w[h][L]. wave -> c-base wid*64.
  U4B8 bfrag[7];
  #pragma unroll
  for (int ks = 0; ks < 7; ++ks)
    bfrag[ks].u = *(const uint4*)&aw[(lane & 15)*116 + ks*16 + (lane >> 4)*4];

  const unsigned short* yn = Yp + (size_t)n*57344;
  const int mr = lane & 15, kq = lane >> 4;
  const int par = mr & 1;
  f32x4 acc[4] = {{0,0,0,0},{0,0,0,0},{0,0,0,0},{0,0,0,0}};
  #pragma unroll
  for (int ks = 0; ks < 7; ++ks) {
    #pragma unroll
    for (int Mt = 0; Mt < 4; ++Mt) {
      const int c2g = (wid*64 + Mt*16 + mr) >> 1;
      const unsigned short* p = yn + c2g*448 + ks*64 + kq*16;
      const uint4 U = *(const uint4*)p;
      const uint4 V = *(const uint4*)(p + 8);
      U4B8 af;
      if (par == 0) {
        af.u.x = (U.x & 0xffffu) | (U.y << 16);
        af.u.y = (U.z & 0xffffu) | (U.w << 16);
        af.u.z = (V.x & 0xffffu) | (V.y << 16);
        af.u.w = (V.z & 0xffffu) | (V.w << 16);
      } else {
        af.u.x = (U.x >> 16) | (U.y & 0xffff0000u);
        af.u.y = (U.z >> 16) | (U.w & 0xffff0000u);
        af.u.z = (V.x >> 16) | (V.y & 0xffff0000u);
        af.u.w = (V.z >> 16) | (V.w & 0xffff0000u);
      }
      acc[Mt] = __builtin_amdgcn_mfma_f32_16x16x32_bf16(af.b, bfrag[ks].b, acc[Mt], 0, 0, 0);
    }
  }

  // D layout: col = lane&15 = h (valid <8), row = (lane>>4)*4 + reg = c-local
  if ((lane & 15) < 8) {
    const int hh = lane & 15;
    #pragma unroll
    for (int Mt = 0; Mt < 4; ++Mt) {
      const int cc = wid*64 + Mt*16 + (lane >> 4)*4;
      pool_s[hh*260 + cc + 0] = acc[Mt][0];
      pool_s[hh*260 + cc + 1] = acc[Mt][1];
      pool_s[hh*260 + cc + 2] = acc[Mt][2];
      pool_s[hh*260 + cc + 3] = acc[Mt][3];
    }
  }
  __syncthreads();
  {
    const int hh = tid >> 5, cc = (tid & 31)*8;
    const float4 o0 = *(const float4*)&pool_s[hh*260 + cc];
    const float4 o1 = *(const float4*)&pool_s[hh*260 + cc + 4];
    float* dst = pooled + (size_t)n*2048 + tid*8;
    *(float4*)(dst)     = o0;
    *(float4*)(dst + 4) = o1;
  }
}

// ---- K3: ctx = wv.pooled + bv ; out = cw.ctx + cb. 8 patches/block, weight reuse. ----
__global__ __launch_bounds__(256) void k3_proj(
    const float* __restrict__ pooled,
    const float* __restrict__ in_w,
    const float* __restrict__ in_b,
    const float* __restrict__ cwT,
    const float* __restrict__ cb,
    float* __restrict__ pout) {
  __shared__ float ctx_s[8*260];
  const int tid = threadIdx.x;
  const int bx = blockIdx.x;
  const int g = (bx & 7)*32 + (bx >> 3);   // XCD swizzle (256 = 8*32)
  const int n0 = g*8;

  // phase 1: ctx[nn][k = tid]
  {
    const int k = tid, hk = k >> 5;
    const float* wv = in_w + (size_t)(512 + k)*256;
    float acc[8] = {0,0,0,0,0,0,0,0};
    for (int c = 0; c < 256; c += 4) {
      const float4 wf = *(const float4*)(wv + c);
      #pragma unroll
      for (int nn = 0; nn < 8; ++nn) {
        const float4 pf = *(const float4*)(pooled + (size_t)(n0 + nn)*2048 + hk*256 + c);
        acc[nn] += wf.x*pf.x + wf.y*pf.y + wf.z*pf.z + wf.w*pf.w;
      }
    }
    const float bvk = in_b[512 + k];
    #pragma unroll
    for (int nn = 0; nn < 8; ++nn) ctx_s[nn*260 + k] = acc[nn] + bvk;
  }
  __syncthreads();
  // phase 2: out[nn][o = tid]
  {
    float oo[8];
    const float cbo = cb[tid];
    #pragma unroll
    for (int nn = 0; nn < 8; ++nn) oo[nn] = cbo;
    for (int kk = 0; kk < 256; ++kk) {
      const float cwv = cwT[kk*256 + tid];
      #pragma unroll
      for (int nn = 0; nn < 8; ++nn) oo[nn] += cwv * ctx_s[nn*260 + kk];
    }
    #pragma unroll
    for (int nn = 0; nn < 8; ++nn) pout[(size_t)(n0 + nn)*256 + tid] = oo[nn];
  }
}

// ---- K4: pout[b][pos][c] -> out[b][c][pos] ----
__global__ void transpose_out(const float* __restrict__ pout, float* __restrict__ out) {
  __shared__ float T[64*65];
  const int b  = blockIdx.x;
  const int pc = blockIdx.y;
  const int cc = blockIdx.z;
  const int tid = threadIdx.x;
  const int lc = tid & 63, lr = tid >> 6;
  #pragma unroll
  for (int i = 0; i < 16; ++i) {
    const int p = i*4 + lr;
    T[p*65 + lc] = pout[((size_t)b*256 + pc*64 + p)*256 + cc*64 + lc];
  }
  __syncthreads();
  #pragma unroll
  for (int i = 0; i < 16; ++i) {
    const int c = i*4 + lr;
    out[((size_t)b*256 + cc*64 + c)*256 + pc*64 + lc] = T[lc*65 + c];
  }
}

extern "C" void kernel_launch(void* const* d_in, const int* in_sizes, int n_in,
                              void* d_out, int out_size, void* d_ws, size_t ws_size,
                              hipStream_t stream) {
  const float* X    = (const float*)d_in[0];
  const float* q    = (const float*)d_in[1];
  const float* in_w = (const float*)d_in[2];
  const float* in_b = (const float*)d_in[3];
  const float* aw   = (const float*)d_in[4];
  const float* aob  = (const float*)d_in[5];
  const float* ow   = (const float*)d_in[6];
  const float* ob   = (const float*)d_in[7];
  float* out = (float*)d_out;

  float* wsf = (float*)d_ws;
  float* qh   = wsf;                               // 256
  float* cb   = wsf + 256;                         // 256
  unsigned short* qk2g = (unsigned short*)(wsf + 512);   // 16x256 bf16 (1024 f)
  float* cwT  = wsf + 4096;                        // 65536
  float* pout = wsf + 69632;                       // 524288
  float* pooled = wsf + 593920;                    // 4194304
  float* Sp   = wsf + 4788224;                     // 14680064
  unsigned short* Yp = (unsigned short*)(wsf + 19468288);  // 2048*57344 ushorts

  hipLaunchKernelGGL(prep1_kernel, dim3(256), dim3(256), 0, stream,
                     q, in_w, in_b, ow, aob, ob, qh, cb);
  hipLaunchKernelGGL(prep2_kernel, dim3(16), dim3(256), 0, stream,
                     qh, in_w, qk2g);
  hipLaunchKernelGGL(prep3_kernel, dim3(256), dim3(256), 0, stream,
                     aw, ow, cwT);
  hipLaunchKernelGGL(k1_repack_scores, dim3(512), dim3(256), 0, stream,
                     X, qk2g, Yp, Sp);
  hipLaunchKernelGGL(k2_pool, dim3(2048), dim3(256), 0, stream,
                     Yp, Sp, pooled);
  hipLaunchKernelGGL(k3_proj, dim3(256), dim3(256), 0, stream,
                     pooled, in_w, in_b, cwT, cb, pout);
  hipLaunchKernelGGL(transpose_out, dim3(8, 4, 4), dim3(256), 0, stream,
                     pout, out);
}

// Round 8
// 344.236 us; speedup vs baseline: 1.2928x; 1.2928x over previous
//
#include <hip/hip_runtime.h>

#define HW_IMG (224*224)
#define SCALE 0.17677669529663687f   // 1/sqrt(32)

typedef short bf16x8 __attribute__((ext_vector_type(8)));
typedef float f32x4 __attribute__((ext_vector_type(4)));
union U4B8 { uint4 u; bf16x8 b; };

__device__ __forceinline__ unsigned bf16rn(float f) {
  unsigned u = __float_as_uint(f);
  return (u + 0x7fffu + ((u >> 16) & 1u)) >> 16;
}
__device__ __forceinline__ unsigned packbf(float a, float b) {
  return bf16rn(a) | (bf16rn(b) << 16);
}

// ---- prep1: qh[r] = in_b[r] + query.in_w[r,:]; cb[r] = out_b[r] + out_w[r,:].aob ----
__global__ void prep1_kernel(const float* __restrict__ query,
                             const float* __restrict__ in_w,
                             const float* __restrict__ in_b,
                             const float* __restrict__ out_w,
                             const float* __restrict__ aob,
                             const float* __restrict__ out_b,
                             float* __restrict__ qh,
                             float* __restrict__ cb) {
  const int r = blockIdx.x, tid = threadIdx.x;
  float p1 = query[tid] * in_w[r*256 + tid];
  float p2 = aob[tid]   * out_w[r*256 + tid];
  #pragma unroll
  for (int o = 32; o; o >>= 1) { p1 += __shfl_xor(p1, o); p2 += __shfl_xor(p2, o); }
  __shared__ float t1[4], t2[4];
  if ((tid & 63) == 0) { t1[tid>>6] = p1; t2[tid>>6] = p2; }
  __syncthreads();
  if (tid == 0) qh[r] = in_b[r] + t1[0]+t1[1]+t1[2]+t1[3];
  if (tid == 1) cb[r] = out_b[r] + t2[0]+t2[1]+t2[2]+t2[3];
}

// ---- prep2: qk2g bf16 [16][256], rows 8..15 zero ----
__global__ void prep2_kernel(const float* __restrict__ qh,
                             const float* __restrict__ in_w,
                             unsigned short* __restrict__ qk2g) {
  const int h = blockIdx.x;   // 0..15
  const int c = threadIdx.x;  // 0..255
  float s = 0.f;
  if (h < 8) {
    #pragma unroll
    for (int d = 0; d < 32; ++d)
      s += qh[h*32 + d] * in_w[(256 + h*32 + d)*256 + c];
    s *= SCALE;
  }
  qk2g[h*256 + c] = (unsigned short)bf16rn(s);
}

// ---- prep3: cwT[t][o] = (out_w @ attn_out_w)[o][t] ----
__global__ void prep3_kernel(const float* __restrict__ aw,
                             const float* __restrict__ out_w,
                             float* __restrict__ cwT) {
  const int o = blockIdx.x, t = threadIdx.x;
  float a = 0.f;
  #pragma unroll 4
  for (int k = 0; k < 256; ++k) a += out_w[o*256 + k] * aw[k*256 + t];
  cwT[t*256 + o] = a;
}

// ---- P1: block=(b, R=pi*7+rr, cg). Streams X (224B runs/ch), LDS tile 64c x 56pos,
//      emits Y3 [n][cg][l'/8][c64][8] bf16 (1KB/wave stores) + Sp scores (MFMA). ----
__global__ __launch_bounds__(256)
__attribute__((amdgpu_waves_per_eu(2, 8)))
void p1_repack_scores(const float* __restrict__ X,
                      const unsigned short* __restrict__ qk2g,
                      unsigned short* __restrict__ Yp,
                      float* __restrict__ Sp) {
  __shared__ float T[64*66];          // [c][pl 56 + pad]; stride 66
  __shared__ float Ss[16*8*32];       // [pj][h][slot32] score staging

  const int tid = threadIdx.x;
  const int lane = tid & 63;
  const int wid = tid >> 6;
  const int bx = blockIdx.x;
  const int g = (bx & 7)*448 + (bx >> 3);   // XCD swizzle (3584 = 8*448)
  const int cg = g & 3;
  const int r2 = g >> 2;                    // 0..895
  const int R = r2 % 112, b = r2 / 112;
  const int pi = R / 7, rr = R % 7;
  const int nbase = (b*16 + pi)*16;

  for (int i = tid; i < 4096; i += 256) Ss[i] = 0.f;

  // fill mapping: 896 float4-units (c, f); id = k*256+tid
  int fc[4], ff[4];
  #pragma unroll
  for (int k = 0; k < 4; ++k) { const int id = k*256 + tid; fc[k] = id/14; ff[k] = id - (id/14)*14; }
  const float* xrow = X + (size_t)(b*256 + cg*64)*HW_IMG + (pi*14 + rr*2)*224;

  // qk A-fragments (global, L1/L2-hot)
  const int hA = lane & 15, kq = lane >> 4, lx = lane & 15;
  U4B8 qa0, qa1;
  qa0.u = *(const uint4*)(qk2g + hA*256 + cg*64 + kq*8);
  qa1.u = *(const uint4*)(qk2g + hA*256 + cg*64 + 32 + kq*8);

  #pragma unroll 1
  for (int tt = 0; tt < 8; ++tt) {
    const int trow = tt >> 2, tcol = (tt & 3)*56;
    // ---- fill tile ----
    #pragma unroll
    for (int k = 0; k < 4; ++k) {
      const int id = k*256 + tid;
      if (id < 896) {
        const float4 v = *(const float4*)(xrow + (size_t)fc[k]*HW_IMG + trow*224 + tcol + ff[k]*4);
        float* d = &T[fc[k]*66 + ff[k]*4];
        d[0] = v.x; d[1] = v.y; d[2] = v.z; d[3] = v.w;
      }
    }
    __syncthreads();

    // ---- (a) Y3 write: per wave-k: (pjl, jgrp); 64 lanes = c -> 1KB contiguous ----
    #pragma unroll
    for (int k = 0; k < 2; ++k) {
      const int q = k*4 + wid;
      const int pjl = q >> 1, jgrp = q & 1;
      const int c = lane;
      unsigned w4[4];
      #pragma unroll
      for (int i = 0; i < 4; ++i) {
        const int jj0 = jgrp*8 + 2*i;
        const float v0 = (jj0     < 14) ? T[c*66 + pjl*14 + jj0]     : 0.f;
        const float v1 = (jj0 + 1 < 14) ? T[c*66 + pjl*14 + jj0 + 1] : 0.f;
        w4[i] = packbf(v0, v1);
      }
      const int n  = nbase + (tt & 3)*4 + pjl;
      const int lg = rr*4 + trow*2 + jgrp;
      *(uint4*)(Yp + ((size_t)((n*4 + cg)*28 + lg)*64 + c)*8) =
          make_uint4(w4[0], w4[1], w4[2], w4[3]);
    }

    // ---- (b) scores: pos-tile = wid; D[h][pos] -> Ss scatter ----
    {
      const int pl = wid*16 + lx;
      f32x4 dd = {0.f, 0.f, 0.f, 0.f};
      #pragma unroll
      for (int s = 0; s < 2; ++s) {
        float fv[8];
        #pragma unroll
        for (int r = 0; r < 8; ++r) fv[r] = T[(s*32 + kq*8 + r)*66 + pl];
        U4B8 bb;
        bb.u.x = packbf(fv[0], fv[1]); bb.u.y = packbf(fv[2], fv[3]);
        bb.u.z = packbf(fv[4], fv[5]); bb.u.w = packbf(fv[6], fv[7]);
        dd = __builtin_amdgcn_mfma_f32_16x16x32_bf16(s ? qa1.b : qa0.b, bb.b, dd, 0, 0, 0);
      }
      if (kq < 2 && pl < 56) {
        const int pjl = (pl*2341) >> 15;       // pl/14
        const int jj  = pl - pjl*14;
        const int base = ((tt & 3)*4 + pjl)*256 + trow*16 + jj;
        #pragma unroll
        for (int rg = 0; rg < 4; ++rg) Ss[base + (kq*4 + rg)*32] = dd[rg];
      }
    }
    __syncthreads();
  }

  // ---- coalesced Sp write: [cg][n][h][l'224] ----
  const size_t spb = (size_t)cg*3670016 + (size_t)nbase*1792;
  #pragma unroll
  for (int k = 0; k < 4; ++k) {
    const int id = k*256 + tid;               // 0..1023
    const int pj = id >> 6, h = (id >> 3) & 7, s4 = id & 7;
    const float4 v = *(const float4*)&Ss[(pj*8 + h)*32 + s4*4];
    *(float4*)(Sp + spb + (size_t)pj*1792 + h*224 + rr*32 + s4*4) = v;
  }
}

// ---- P2: per patch: reduce Sp over cg, softmax, write W bf16 [n][h16][l'224] ----
__global__ __launch_bounds__(256) void p2_softmax(const float* __restrict__ Sp,
                                                  unsigned short* __restrict__ W) {
  __shared__ float sm[1792];
  const int tid = threadIdx.x;
  const int bid = blockIdx.x;
  const int n = (bid & 7)*256 + (bid >> 3);
  const float* s0 = Sp + (size_t)n*1792;
  #pragma unroll
  for (int j = 0; j < 7; ++j) {
    const int id = tid + 256*j;
    sm[id] = s0[id] + s0[3670016 + id] + s0[2*3670016 + id] + s0[3*3670016 + id];
  }
  __syncthreads();
  const int h = tid >> 5, l = tid & 31;
  float sv[7]; bool mk[7];
  float mx = -1e30f;
  #pragma unroll
  for (int j = 0; j < 7; ++j) {
    const int ls = l + 32*j;
    sv[j] = sm[h*224 + ls];
    mk[j] = (ls & 15) < 14;
    if (mk[j]) mx = fmaxf(mx, sv[j]);
  }
  #pragma unroll
  for (int o = 16; o; o >>= 1) mx = fmaxf(mx, __shfl_xor(mx, o, 32));
  float d = 0.f;
  #pragma unroll
  for (int j = 0; j < 7; ++j) {
    sv[j] = mk[j] ? __expf(sv[j] - mx) : 0.f;
    d += sv[j];
  }
  #pragma unroll
  for (int o = 16; o; o >>= 1) d += __shfl_xor(d, o, 32);
  const float inv = 1.f / d;
  unsigned* wn = (unsigned*)(W + (size_t)n*3584);
  #pragma unroll
  for (int j = 0; j < 7; ++j) {
    const float w = sv[j] * inv;
    const float w2 = __shfl_xor(w, 1, 32);
    if (!(l & 1)) wn[h*112 + ((l + 32*j) >> 1)] = packbf(w, w2);
  }
  for (int i = tid; i < 896; i += 256) wn[896 + i] = 0u;   // heads 8..15 = 0
}

// ---- P3: pooling GEMM per patch, zero LDS, zero barriers.
//      pooled[n][h8][c256] = sum_l' Y3[c][l'] * W[l'][h] ----
__global__ __launch_bounds__(256)
__attribute__((amdgpu_waves_per_eu(2, 8)))
void p3_pool(const unsigned short* __restrict__ Yp,
             const unsigned short* __restrict__ W,
             float* __restrict__ pooled) {
  const int tid = threadIdx.x, lane = tid & 63, wid = tid >> 6;
  const int bid = blockIdx.x;
  const int n = (bid & 7)*256 + (bid >> 3);   // XCD swizzle
  const int hc = lane & 15, kq = lane >> 4;

  U4B8 bw[7];
  const unsigned short* wn = W + (size_t)n*3584;
  #pragma unroll
  for (int ks = 0; ks < 7; ++ks)
    bw[ks].u = *(const uint4*)(wn + hc*224 + ks*32 + kq*8);

  const unsigned short* yb = Yp + ((size_t)n*4 + wid)*28*512;   // cg = wid
  f32x4 acc[4] = {{0,0,0,0},{0,0,0,0},{0,0,0,0},{0,0,0,0}};
  #pragma unroll
  for (int ks = 0; ks < 7; ++ks) {
    #pragma unroll
    for (int Mt = 0; Mt < 4; ++Mt) {
      U4B8 ay;
      ay.u = *(const uint4*)(yb + (size_t)((ks*4 + kq)*64 + Mt*16 + hc)*8);
      acc[Mt] = __builtin_amdgcn_mfma_f32_16x16x32_bf16(ay.b, bw[ks].b, acc[Mt], 0, 0, 0);
    }
  }
  if (hc < 8) {
    float* pb = pooled + (size_t)n*2048 + hc*256 + wid*64;
    #pragma unroll
    for (int Mt = 0; Mt < 4; ++Mt)
      *(float4*)(pb + Mt*16 + kq*4) =
          make_float4(acc[Mt][0], acc[Mt][1], acc[Mt][2], acc[Mt][3]);
  }
}

// ---- K3: ctx = wv.pooled + bv ; out = cw.ctx + cb. 8 patches/block. ----
__global__ __launch_bounds__(256) void k3_proj(
    const float* __restrict__ pooled,
    const float* __restrict__ in_w,
    const float* __restrict__ in_b,
    const float* __restrict__ cwT,
    const float* __restrict__ cb,
    float* __restrict__ pout) {
  __shared__ float ctx_s[8*260];
  const int tid = threadIdx.x;
  const int bx = blockIdx.x;
  const int g = (bx & 7)*32 + (bx >> 3);   // XCD swizzle (256 = 8*32)
  const int n0 = g*8;
  {
    const int k = tid, hk = k >> 5;
    const float* wv = in_w + (size_t)(512 + k)*256;
    float acc[8] = {0,0,0,0,0,0,0,0};
    for (int c = 0; c < 256; c += 4) {
      const float4 wf = *(const float4*)(wv + c);
      #pragma unroll
      for (int nn = 0; nn < 8; ++nn) {
        const float4 pf = *(const float4*)(pooled + (size_t)(n0 + nn)*2048 + hk*256 + c);
        acc[nn] += wf.x*pf.x + wf.y*pf.y + wf.z*pf.z + wf.w*pf.w;
      }
    }
    const float bvk = in_b[512 + k];
    #pragma unroll
    for (int nn = 0; nn < 8; ++nn) ctx_s[nn*260 + k] = acc[nn] + bvk;
  }
  __syncthreads();
  {
    float oo[8];
    const float cbo = cb[tid];
    #pragma unroll
    for (int nn = 0; nn < 8; ++nn) oo[nn] = cbo;
    for (int kk = 0; kk < 256; ++kk) {
      const float cwv = cwT[kk*256 + tid];
      #pragma unroll
      for (int nn = 0; nn < 8; ++nn) oo[nn] += cwv * ctx_s[nn*260 + kk];
    }
    #pragma unroll
    for (int nn = 0; nn < 8; ++nn) pout[(size_t)(n0 + nn)*256 + tid] = oo[nn];
  }
}

// ---- K4: pout[b][pos][c] -> out[b][c][pos] ----
__global__ void transpose_out(const float* __restrict__ pout, float* __restrict__ out) {
  __shared__ float T[64*65];
  const int b  = blockIdx.x;
  const int pc = blockIdx.y;
  const int cc = blockIdx.z;
  const int tid = threadIdx.x;
  const int lc = tid & 63, lr = tid >> 6;
  #pragma unroll
  for (int i = 0; i < 16; ++i) {
    const int p = i*4 + lr;
    T[p*65 + lc] = pout[((size_t)b*256 + pc*64 + p)*256 + cc*64 + lc];
  }
  __syncthreads();
  #pragma unroll
  for (int i = 0; i < 16; ++i) {
    const int c = i*4 + lr;
    out[((size_t)b*256 + cc*64 + c)*256 + pc*64 + lc] = T[lc*65 + c];
  }
}

extern "C" void kernel_launch(void* const* d_in, const int* in_sizes, int n_in,
                              void* d_out, int out_size, void* d_ws, size_t ws_size,
                              hipStream_t stream) {
  const float* X    = (const float*)d_in[0];
  const float* q    = (const float*)d_in[1];
  const float* in_w = (const float*)d_in[2];
  const float* in_b = (const float*)d_in[3];
  const float* aw   = (const float*)d_in[4];
  const float* aob  = (const float*)d_in[5];
  const float* ow   = (const float*)d_in[6];
  const float* ob   = (const float*)d_in[7];
  float* out = (float*)d_out;

  float* wsf = (float*)d_ws;
  float* qh   = wsf;                               // 256
  float* cb   = wsf + 256;                         // 256
  unsigned short* qk2g = (unsigned short*)(wsf + 512);   // 16x256 bf16 (2048 f)
  float* cwT  = wsf + 4096;                        // 65536 -> 69632
  float* Sp   = wsf + 69632;                       // 14680064 -> 14749696
  unsigned short* W = (unsigned short*)(wsf + 14749696); // 3670016 f -> 18419712
  unsigned short* Yp = (unsigned short*)(wsf + 18419712);// 58720256 f -> 77139968
  // overlays (Sp dead after p2; reuse its space)
  float* pooled = wsf + 69632;                     // 4194304 (< Sp size)
  float* pout   = wsf + 69632 + 4194304;           // 524288  (still < Sp size)

  hipLaunchKernelGGL(prep1_kernel, dim3(256), dim3(256), 0, stream,
                     q, in_w, in_b, ow, aob, ob, qh, cb);
  hipLaunchKernelGGL(prep2_kernel, dim3(16), dim3(256), 0, stream,
                     qh, in_w, qk2g);
  hipLaunchKernelGGL(prep3_kernel, dim3(256), dim3(256), 0, stream,
                     aw, ow, cwT);
  hipLaunchKernelGGL(p1_repack_scores, dim3(3584), dim3(256), 0, stream,
                     X, qk2g, Yp, Sp);
  hipLaunchKernelGGL(p2_softmax, dim3(2048), dim3(256), 0, stream,
                     Sp, W);
  hipLaunchKernelGGL(p3_pool, dim3(2048), dim3(256), 0, stream,
                     Yp, W, pooled);
  hipLaunchKernelGGL(k3_proj, dim3(256), dim3(256), 0, stream,
                     pooled, in_w, in_b, cwT, cb, pout);
  hipLaunchKernelGGL(transpose_out, dim3(8, 4, 4), dim3(256), 0, stream,
                     pout, out);
}